// Round 11
// baseline (525.127 us; speedup 1.0000x reference)
//
#include <hip/hip_runtime.h>
#include <stdint.h>

typedef __attribute__((ext_vector_type(8))) _Float16 f16x8;
typedef __attribute__((ext_vector_type(4))) float f32x4;

#define N_NODES 4096
#define N_EDGES 32768

__device__ __forceinline__ float sigm(float x) { return 1.f / (1.f + __expf(-x)); }

// pack 8 consecutive f32 -> f16x8 (RNE)
__device__ __forceinline__ f16x8 packh8(const float* p) {
  f16x8 r;
#pragma unroll
  for (int i = 0; i < 8; ++i) r[i] = (_Float16)p[i];
  return r;
}

// ---------------------------------------------------------------------------
__global__ void zero_agg_kernel(float* __restrict__ agg) {
  agg[blockIdx.x * 256 + threadIdx.x] = 0.f;
}

// ---------------------------------------------------------------------------
// prep (merged): blocks 0..127  -> WnnT[n][k] fp16 from Wnn[k][n] f32
//                blocks 128..319 -> We1T / We2T fp16 transposes
// ---------------------------------------------------------------------------
__global__ void prep_all(const float* __restrict__ Wnn,
                         const float* __restrict__ We1,
                         const float* __restrict__ We2,
                         _Float16* __restrict__ WnnT,
                         _Float16* __restrict__ We1T,
                         _Float16* __restrict__ We2T) {
  __shared__ float tile[128][33];
  const int b = blockIdx.x, t = threadIdx.x;
  if (b < 128) {
    const int nb = b * 32;
    for (int i = 0; i < 16; ++i) {
      int g = i * 256 + t;          // 4096 = 128k x 32n
      int k = g >> 5, j = g & 31;
      tile[k][j] = Wnn[(size_t)k * 4096 + nb + j];
    }
    __syncthreads();
    for (int i = 0; i < 16; ++i) {
      int g = i * 256 + t;
      int j = g >> 7, k = g & 127;
      WnnT[(size_t)(nb + j) * 128 + k] = (_Float16)tile[k][j];
    }
  } else {
    int idx = (b - 128) * 256 + t;   // < 49152
    if (idx < 32768) {
      int n = idx >> 8, k = idx & 255;
      We1T[idx] = (_Float16)We1[(size_t)k * 128 + n];
    } else {
      int j = idx - 32768;
      int n = j >> 7, k = j & 127;
      We2T[j] = (_Float16)We2[(size_t)k * 128 + n];
    }
  }
}

// ---------------------------------------------------------------------------
// proj_node: h = relu(node_feats @ W_p + b_p) -> hid f32 (in d_out)
// ---------------------------------------------------------------------------
__global__ void proj_node_f(const float* __restrict__ nf,
                            const float* __restrict__ Wp,
                            const float* __restrict__ bp,
                            float* __restrict__ h) {
  int idx = blockIdx.x * 256 + threadIdx.x;
  int n = idx >> 6, c = idx & 63;
  float acc = bp[c];
  for (int k = 0; k < 64; ++k)
    acc = fmaf(nf[n * 64 + k], Wp[k * 64 + c], acc);
  h[idx] = fmaxf(acc, 0.f);
}

// ---------------------------------------------------------------------------
// proj_edge: e = relu(edge_attr @ W_pe + b_pe); Wpe cached in LDS; 32 e/block.
// ---------------------------------------------------------------------------
__launch_bounds__(256)
__global__ void proj_edge_f2(const float* __restrict__ ea,
                             const float* __restrict__ Wpe,
                             const float* __restrict__ bpe,
                             float* __restrict__ e) {
  __shared__ float sw[16 * 128];
  __shared__ float sb[128];
  __shared__ float sa[32][17];
  const int t = threadIdx.x;
  const int ebase = blockIdx.x * 32;
  for (int g = t; g < 2048; g += 256) sw[g] = Wpe[g];
  if (t < 128) sb[t] = bpe[t];
  for (int g = t; g < 512; g += 256) {
    int r = g >> 4, k = g & 15;
    sa[r][k] = ea[(size_t)(ebase + r) * 16 + k];
  }
  __syncthreads();
  int c = t & 127, eg = t >> 7;
  float wc[16];
#pragma unroll
  for (int k = 0; k < 16; ++k) wc[k] = sw[k * 128 + c];
  float bv = sb[c];
#pragma unroll
  for (int i = 0; i < 16; ++i) {
    int ee = eg * 16 + i;
    float acc = bv;
#pragma unroll
    for (int k = 0; k < 16; ++k) acc = fmaf(sa[ee][k], wc[k], acc);
    e[(size_t)(ebase + ee) * 128 + c] = fmaxf(acc, 0.f);
  }
}

// ---------------------------------------------------------------------------
// fused_msg (MFMA fp16 v6): 1024 blocks = 512 e-tiles x 2 d-halves, 256 thr.
// R6/R9/R10 all ~75us at 1 block/CU (8 waves): latency-bound, not LDS/conflict
// bound (R10 fixed conflicts 8.8M->0.46M for +0%). Fix: 4x more blocks, LDS
// 25KB -> 4 blocks/CU resident = 16 waves/CU (2x TLP). Each block does a
// 32-chunk d-half; partial msg atomically added (agg gets 2 partials/(e,f)).
// Wave: 64 edges x 16 f (fw). bb[2][4]=32 VGPR per dg body; ~95 VGPR total.
// Ae XOR-swizzled (conflict-free, verified R10).
// ---------------------------------------------------------------------------
__launch_bounds__(256, 4)
__global__ void fused_msg_m(const float* __restrict__ ebf,
                            const float* __restrict__ hid,
                            const _Float16* __restrict__ WnnT,
                            const float* __restrict__ bnn,
                            const int* __restrict__ eidx,
                            float* __restrict__ agg) {
  __shared__ __align__(16) _Float16 Ae[64 * 128];   // 16,384 B, XOR-swizzled
  __shared__ __align__(16) float Hs[32 * 68];       // 8,704 B  Hs[dl*68+e]
  const int t = threadIdx.x;       // 0..255
  const int fw = t >> 6, l = t & 63, l15 = l & 15, q = l >> 4;
  const int eb = blockIdx.x >> 1;
  const int dh = blockIdx.x & 1;
  const int ebase = eb * 64;
  const int dbase = dh * 32;

  // stage Hs: 64 e x 8 local-d-quads (d = dbase + 0..31)
#pragma unroll
  for (int i = 0; i < 2; ++i) {
    int g = i * 256 + t;           // 512 = 64 e x 8 d4
    int e = g >> 3, d4 = g & 7;
    int r = eidx[ebase + e];
    float4 v = *(const float4*)&hid[(size_t)r * 64 + dbase + d4 * 4];
    Hs[(d4 * 4 + 0) * 68 + e] = v.x;
    Hs[(d4 * 4 + 1) * 68 + e] = v.y;
    Hs[(d4 * 4 + 2) * 68 + e] = v.z;
    Hs[(d4 * 4 + 3) * 68 + e] = v.w;
  }
  // stage Ae: 64 edges x 128 k, f32 -> fp16 once, XOR-swizzled 16B blocks
#pragma unroll
  for (int i = 0; i < 4; ++i) {
    int g = i * 256 + t;           // 1024 = 64 e x 16 kg
    int e = g >> 4, kg = g & 15;
    f16x8 v = packh8(&ebf[(size_t)(ebase + e) * 128 + kg * 8]);
    int kgp = kg ^ (e & 15);
    *(f16x8*)&Ae[e * 128 + kgp * 8] = v;
  }

  float msg[4][4];
#pragma unroll
  for (int m = 0; m < 4; ++m)
#pragma unroll
    for (int rr = 0; rr < 4; ++rr) msg[m][rr] = 0.f;

  __syncthreads();

  // B fragment base: lane row within chunk = fw*16+l15, k-offset q*8
  const _Float16* wb = WnnT + (size_t)(fw * 16 + l15) * 128 + q * 8;

#pragma unroll 1
  for (int dg = 0; dg < 16; ++dg) {
    const int d0 = dbase + dg * 2;
    f16x8 bb[2][4];
#pragma unroll
    for (int c = 0; c < 2; ++c) {
      const _Float16* p = wb + (size_t)(d0 + c) * 8192;
#pragma unroll
      for (int kk = 0; kk < 4; ++kk) bb[c][kk] = *(const f16x8*)(p + kk * 32);
    }
    float bnv[2];
#pragma unroll
    for (int c = 0; c < 2; ++c) bnv[c] = bnn[(d0 + c) * 64 + fw * 16 + l15];

#pragma unroll
    for (int m = 0; m < 4; ++m) {
      const int arow = (m * 16 + l15) * 128;
      f32x4 C[2];
      C[0] = (f32x4){0.f, 0.f, 0.f, 0.f};
      C[1] = (f32x4){0.f, 0.f, 0.f, 0.f};
#pragma unroll
      for (int kk = 0; kk < 4; ++kk) {
        int kgp = (kk * 4 + q) ^ l15;   // e&15 == l15 for this wave's A rows
        f16x8 a = *(const f16x8*)&Ae[arow + kgp * 8];
        C[0] = __builtin_amdgcn_mfma_f32_16x16x32_f16(a, bb[0][kk], C[0], 0, 0, 0);
        C[1] = __builtin_amdgcn_mfma_f32_16x16x32_f16(a, bb[1][kk], C[1], 0, 0, 0);
      }
#pragma unroll
      for (int c = 0; c < 2; ++c) {
        int dl = dg * 2 + c;
        float4 hv = *(const float4*)&Hs[dl * 68 + m * 16 + q * 4];
        msg[m][0] = fmaf(hv.x, fmaxf(C[c][0] + bnv[c], 0.f), msg[m][0]);
        msg[m][1] = fmaf(hv.y, fmaxf(C[c][1] + bnv[c], 0.f), msg[m][1]);
        msg[m][2] = fmaf(hv.z, fmaxf(C[c][2] + bnv[c], 0.f), msg[m][2]);
        msg[m][3] = fmaf(hv.w, fmaxf(C[c][3] + bnv[c], 0.f), msg[m][3]);
      }
    }
    asm volatile("" ::: "memory");   // keep LDS A-reads in-loop (no VGPR hoist)
  }

  const int* colp = eidx + N_EDGES;
#pragma unroll
  for (int m = 0; m < 4; ++m)
#pragma unroll
    for (int rr = 0; rr < 4; ++rr) {
      int col = colp[ebase + m * 16 + q * 4 + rr];
      atomicAdd(&agg[(size_t)col * 64 + fw * 16 + l15], msg[m][rr]);
    }
}

// ---------------------------------------------------------------------------
// node_update: m = relu(agg + h@W_root + b_conv); GRU; hid (f32, d_out) in
// place. Also zeroes its own agg slice for the next step (same thread reads
// then zeroes -> no hazard).
// ---------------------------------------------------------------------------
__global__ void node_update_f(const float* __restrict__ agg_r,
                              float* __restrict__ agg_w,
                              float* __restrict__ hid,
                              const float* __restrict__ Wroot,
                              const float* __restrict__ bconv,
                              const float* __restrict__ wih,
                              const float* __restrict__ whh,
                              const float* __restrict__ bih,
                              const float* __restrict__ bhh) {
  __shared__ __align__(16) float sh[16 * 64];
  __shared__ __align__(16) float sm[16 * 64];
  __shared__ __align__(16) float sg[16 * 384];
  const int t = threadIdx.x;
  const int nb = blockIdx.x * 16;

  for (int i = 0; i < 4; ++i) sh[i * 256 + t] = hid[nb * 64 + i * 256 + t];
  __syncthreads();

  for (int i = 0; i < 4; ++i) {
    int idx = i * 256 + t;
    int nl = idx >> 6, dc = idx & 63;
    float acc = bconv[dc] + agg_r[nb * 64 + idx];
    for (int k = 0; k < 64; ++k)
      acc = fmaf(sh[nl * 64 + k], Wroot[k * 64 + dc], acc);
    sm[idx] = fmaxf(acc, 0.f);
  }
  __syncthreads();

  for (int i = 0; i < 24; ++i) {
    int idx = i * 256 + t;
    int nl = idx / 384, j2 = idx % 384;
    float acc;
    if (j2 < 192) {
      acc = bih[j2];
      for (int k = 0; k < 64; ++k)
        acc = fmaf(sm[nl * 64 + k], wih[k * 192 + j2], acc);
    } else {
      int j = j2 - 192;
      acc = bhh[j];
      for (int k = 0; k < 64; ++k)
        acc = fmaf(sh[nl * 64 + k], whh[k * 192 + j], acc);
    }
    sg[idx] = acc;
  }
  __syncthreads();

  for (int i = 0; i < 4; ++i) {
    int idx = i * 256 + t;
    int nl = idx >> 6, dc = idx & 63;
    const float* g = &sg[nl * 384];
    float ir = g[dc], iz = g[64 + dc], in_ = g[128 + dc];
    float hr = g[192 + dc], hz = g[256 + dc], hn = g[320 + dc];
    float r = sigm(ir + hr), z = sigm(iz + hz);
    float nc = tanhf(in_ + r * hn);
    hid[nb * 64 + idx] = (1.f - z) * nc + z * sh[nl * 64 + dc];
    agg_w[nb * 64 + idx] = 0.f;   // ready for next step's atomics
  }
}

// ---------------------------------------------------------------------------
// edge_mlp (MFMA, fp16): e' = relu(relu([h[row]|h[col]|e] @ We1 + b1) @ We2 + b2)
// 64 edges/block. cat staged to LDS as fp16; B fragments direct from global
// (per-wave disjoint rows). Hidden tile Ts in LDS (fp16). f32 in/out, in place.
// ---------------------------------------------------------------------------
__launch_bounds__(256)
__global__ void edge_mlp_m(const float* __restrict__ hid,
                           float* __restrict__ ebf,
                           const int* __restrict__ eidx,
                           const _Float16* __restrict__ We1T,
                           const float* __restrict__ be1,
                           const _Float16* __restrict__ We2T,
                           const float* __restrict__ be2) {
  __shared__ _Float16 As[64 * 264];   // 33,792 B
  __shared__ _Float16 Ts[64 * 136];   // 17,408 B
  const int t = threadIdx.x;
  const int w = t >> 6, l = t & 63, l15 = l & 15, q = l >> 4;
  const int mbase = blockIdx.x * 64;

  for (int g = t; g < 2048; g += 256) {
    int r = g >> 5, kg = g & 31;
    int e = mbase + r;
    const float* src;
    if (kg < 8)       src = &hid[(size_t)eidx[e] * 64 + kg * 8];
    else if (kg < 16) src = &hid[(size_t)eidx[N_EDGES + e] * 64 + (kg - 8) * 8];
    else              src = &ebf[(size_t)e * 128 + (kg - 16) * 8];
    *(f16x8*)&As[r * 264 + kg * 8] = packh8(src);
  }
  __syncthreads();

  f32x4 zero4 = {0.f, 0.f, 0.f, 0.f};
  f32x4 acc[4][2];
#pragma unroll
  for (int m = 0; m < 4; ++m)
#pragma unroll
    for (int nn = 0; nn < 2; ++nn) acc[m][nn] = zero4;

#pragma unroll
  for (int kc = 0; kc < 4; ++kc)
#pragma unroll
    for (int kk = 0; kk < 2; ++kk) {
      int ko = kc * 64 + kk * 32 + q * 8;
      f16x8 b0 = *(const f16x8*)(We1T + (size_t)(w * 32 + l15) * 256 + ko);
      f16x8 b1 = *(const f16x8*)(We1T + (size_t)(w * 32 + 16 + l15) * 256 + ko);
#pragma unroll
      for (int m = 0; m < 4; ++m) {
        f16x8 a = *(const f16x8*)&As[(m * 16 + l15) * 264 + ko];
        acc[m][0] = __builtin_amdgcn_mfma_f32_16x16x32_f16(a, b0, acc[m][0], 0, 0, 0);
        acc[m][1] = __builtin_amdgcn_mfma_f32_16x16x32_f16(a, b1, acc[m][1], 0, 0, 0);
      }
    }

#pragma unroll
  for (int m = 0; m < 4; ++m)
#pragma unroll
    for (int nn = 0; nn < 2; ++nn) {
      int col = w * 32 + nn * 16 + l15;
      float bv = be1[col];
#pragma unroll
      for (int rr = 0; rr < 4; ++rr) {
        int row = m * 16 + q * 4 + rr;
        Ts[row * 136 + col] = (_Float16)fmaxf(acc[m][nn][rr] + bv, 0.f);
      }
    }
  __syncthreads();

  f32x4 acc2[4][2];
#pragma unroll
  for (int m = 0; m < 4; ++m)
#pragma unroll
    for (int nn = 0; nn < 2; ++nn) acc2[m][nn] = zero4;

#pragma unroll
  for (int kc = 0; kc < 2; ++kc)
#pragma unroll
    for (int kk = 0; kk < 2; ++kk) {
      int ko = kc * 64 + kk * 32 + q * 8;
      f16x8 b0 = *(const f16x8*)(We2T + (size_t)(w * 32 + l15) * 128 + ko);
      f16x8 b1 = *(const f16x8*)(We2T + (size_t)(w * 32 + 16 + l15) * 128 + ko);
#pragma unroll
      for (int m = 0; m < 4; ++m) {
        f16x8 a = *(const f16x8*)&Ts[(m * 16 + l15) * 136 + ko];
        acc2[m][0] = __builtin_amdgcn_mfma_f32_16x16x32_f16(a, b0, acc2[m][0], 0, 0, 0);
        acc2[m][1] = __builtin_amdgcn_mfma_f32_16x16x32_f16(a, b1, acc2[m][1], 0, 0, 0);
      }
    }

#pragma unroll
  for (int m = 0; m < 4; ++m)
#pragma unroll
    for (int nn = 0; nn < 2; ++nn) {
      int col = w * 32 + nn * 16 + l15;
      float bv = be2[col];
#pragma unroll
      for (int rr = 0; rr < 4; ++rr) {
        int row = mbase + m * 16 + q * 4 + rr;
        ebf[(size_t)row * 128 + col] = fmaxf(acc2[m][nn][rr] + bv, 0.f);
      }
    }
}

// ---------------------------------------------------------------------------
extern "C" void kernel_launch(void* const* d_in, const int* in_sizes, int n_in,
                              void* d_out, int out_size, void* d_ws, size_t ws_size,
                              hipStream_t stream) {
  const float* nf    = (const float*)d_in[0];
  const float* ea    = (const float*)d_in[1];
  const int*   eidx  = (const int*)d_in[2];
  const float* Wp    = (const float*)d_in[3];
  const float* bp    = (const float*)d_in[4];
  const float* Wpe   = (const float*)d_in[5];
  const float* bpe   = (const float*)d_in[6];
  const float* Wnn   = (const float*)d_in[7];
  const float* bnn   = (const float*)d_in[8];
  const float* Wroot = (const float*)d_in[9];
  const float* bconv = (const float*)d_in[10];
  const float* wih   = (const float*)d_in[11];
  const float* whh   = (const float*)d_in[12];
  const float* bih   = (const float*)d_in[13];
  const float* bhh   = (const float*)d_in[14];
  const float* We1   = (const float*)d_in[15];
  const float* be1   = (const float*)d_in[16];
  const float* We2   = (const float*)d_in[17];
  const float* be2   = (const float*)d_in[18];

  // h and e live in d_out (f32 masters), fully rewritten every launch.
  float* hid = (float*)d_out;                 // 4096*64
  float* ebf = (float*)d_out + 4096 * 64;     // 32768*128

  // workspace: 2,195,456 B
  char* ws = (char*)d_ws;
  _Float16* WnnT = (_Float16*)(ws + 0);          // 1,048,576
  _Float16* We1T = (_Float16*)(ws + 1048576);    //    65,536
  _Float16* We2T = (_Float16*)(ws + 1114112);    //    32,768
  float*    agg  = (float*)(ws + 1146880);       // 1,048,576

  prep_all<<<320, 256, 0, stream>>>(Wnn, We1, We2, WnnT, We1T, We2T);
  proj_node_f<<<1024, 256, 0, stream>>>(nf, Wp, bp, hid);
  proj_edge_f2<<<1024, 256, 0, stream>>>(ea, Wpe, bpe, ebf);
  zero_agg_kernel<<<1024, 256, 0, stream>>>(agg);

  for (int s = 0; s < 3; ++s) {
    fused_msg_m<<<1024, 256, 0, stream>>>(ebf, hid, WnnT, bnn, eidx, agg);
    node_update_f<<<256, 256, 0, stream>>>(agg, agg, hid, Wroot, bconv,
                                           wih, whh, bih, bhh);
    edge_mlp_m<<<512, 256, 0, stream>>>(hid, ebf, eidx, We1T, be1, We2T, be2);
  }
}

// Round 12
// 469.982 us; speedup vs baseline: 1.1173x; 1.1173x over previous
//
#include <hip/hip_runtime.h>
#include <stdint.h>

typedef __attribute__((ext_vector_type(8))) _Float16 f16x8;
typedef __attribute__((ext_vector_type(4))) float f32x4;

#define N_NODES 4096
#define N_EDGES 32768

__device__ __forceinline__ float sigm(float x) { return 1.f / (1.f + __expf(-x)); }

// pack 8 consecutive f32 -> f16x8 (RNE)
__device__ __forceinline__ f16x8 packh8(const float* p) {
  f16x8 r;
#pragma unroll
  for (int i = 0; i < 8; ++i) r[i] = (_Float16)p[i];
  return r;
}

// ---------------------------------------------------------------------------
// prep (merged): blocks 0..127  -> WnnT[n][k] fp16 from Wnn[k][n] f32
//                blocks 128..319 -> We1T / We2T fp16 transposes
// ---------------------------------------------------------------------------
__global__ void prep_all(const float* __restrict__ Wnn,
                         const float* __restrict__ We1,
                         const float* __restrict__ We2,
                         _Float16* __restrict__ WnnT,
                         _Float16* __restrict__ We1T,
                         _Float16* __restrict__ We2T) {
  __shared__ float tile[128][33];
  const int b = blockIdx.x, t = threadIdx.x;
  if (b < 128) {
    const int nb = b * 32;
    for (int i = 0; i < 16; ++i) {
      int g = i * 256 + t;          // 4096 = 128k x 32n
      int k = g >> 5, j = g & 31;
      tile[k][j] = Wnn[(size_t)k * 4096 + nb + j];
    }
    __syncthreads();
    for (int i = 0; i < 16; ++i) {
      int g = i * 256 + t;
      int j = g >> 7, k = g & 127;
      WnnT[(size_t)(nb + j) * 128 + k] = (_Float16)tile[k][j];
    }
  } else {
    int idx = (b - 128) * 256 + t;   // < 49152
    if (idx < 32768) {
      int n = idx >> 8, k = idx & 255;
      We1T[idx] = (_Float16)We1[(size_t)k * 128 + n];
    } else {
      int j = idx - 32768;
      int n = j >> 7, k = j & 127;
      We2T[j] = (_Float16)We2[(size_t)k * 128 + n];
    }
  }
}

// ---------------------------------------------------------------------------
// CSR build (once per launch; edge_index is launch-constant)
// ---------------------------------------------------------------------------
__global__ void csr_zero(int* __restrict__ rowcnt) {
  rowcnt[blockIdx.x * 256 + threadIdx.x] = 0;
}
__global__ void csr_count(const int* __restrict__ eidx, int* __restrict__ rowcnt) {
  int e = blockIdx.x * 256 + threadIdx.x;
  atomicAdd(&rowcnt[eidx[N_EDGES + e]], 1);
}
__global__ void csr_scan(const int* __restrict__ rowcnt,
                         int* __restrict__ rowptr, int* __restrict__ cursor) {
  __shared__ int part[1024];
  const int t = threadIdx.x;
  const int base = t * 4;
  int s0 = rowcnt[base], s1 = rowcnt[base + 1], s2 = rowcnt[base + 2], s3 = rowcnt[base + 3];
  int sum = s0 + s1 + s2 + s3;
  part[t] = sum;
  __syncthreads();
  for (int off = 1; off < 1024; off <<= 1) {
    int v = (t >= off) ? part[t - off] : 0;
    __syncthreads();
    part[t] += v;
    __syncthreads();
  }
  int excl = part[t] - sum;
  int p0 = excl, p1 = excl + s0, p2 = excl + s0 + s1, p3 = excl + s0 + s1 + s2;
  rowptr[base] = p0; rowptr[base + 1] = p1; rowptr[base + 2] = p2; rowptr[base + 3] = p3;
  cursor[base] = p0; cursor[base + 1] = p1; cursor[base + 2] = p2; cursor[base + 3] = p3;
  if (t == 0) rowptr[4096] = N_EDGES;
}
__global__ void csr_fill(const int* __restrict__ eidx, int* __restrict__ cursor,
                         int* __restrict__ eids) {
  int e = blockIdx.x * 256 + threadIdx.x;
  int slot = atomicAdd(&cursor[eidx[N_EDGES + e]], 1);
  eids[slot] = e;
}

// ---------------------------------------------------------------------------
// proj_node: h = relu(node_feats @ W_p + b_p) -> hid f32 (in d_out)
// ---------------------------------------------------------------------------
__global__ void proj_node_f(const float* __restrict__ nf,
                            const float* __restrict__ Wp,
                            const float* __restrict__ bp,
                            float* __restrict__ h) {
  int idx = blockIdx.x * 256 + threadIdx.x;
  int n = idx >> 6, c = idx & 63;
  float acc = bp[c];
  for (int k = 0; k < 64; ++k)
    acc = fmaf(nf[n * 64 + k], Wp[k * 64 + c], acc);
  h[idx] = fmaxf(acc, 0.f);
}

// ---------------------------------------------------------------------------
// proj_edge: e = relu(edge_attr @ W_pe + b_pe); Wpe cached in LDS; 32 e/block.
// ---------------------------------------------------------------------------
__launch_bounds__(256)
__global__ void proj_edge_f2(const float* __restrict__ ea,
                             const float* __restrict__ Wpe,
                             const float* __restrict__ bpe,
                             float* __restrict__ e) {
  __shared__ float sw[16 * 128];
  __shared__ float sb[128];
  __shared__ float sa[32][17];
  const int t = threadIdx.x;
  const int ebase = blockIdx.x * 32;
  for (int g = t; g < 2048; g += 256) sw[g] = Wpe[g];
  if (t < 128) sb[t] = bpe[t];
  for (int g = t; g < 512; g += 256) {
    int r = g >> 4, k = g & 15;
    sa[r][k] = ea[(size_t)(ebase + r) * 16 + k];
  }
  __syncthreads();
  int c = t & 127, eg = t >> 7;
  float wc[16];
#pragma unroll
  for (int k = 0; k < 16; ++k) wc[k] = sw[k * 128 + c];
  float bv = sb[c];
#pragma unroll
  for (int i = 0; i < 16; ++i) {
    int ee = eg * 16 + i;
    float acc = bv;
#pragma unroll
    for (int k = 0; k < 16; ++k) acc = fmaf(sa[ee][k], wc[k], acc);
    e[(size_t)(ebase + ee) * 128 + c] = fmaxf(acc, 0.f);
  }
}

// ---------------------------------------------------------------------------
// fused_msg (MFMA fp16 v7): 256 blocks x 512 threads (R10 structure, best
// measured). Changes vs R10: (1) atomics removed -> fp16 stores to per-edge
// msgbuf (R10->R11 A/B showed ~4ns/atomic marginal cost); (2) d-loop starts
// at rotation blockIdx%16 -> blocks sweep different B chunks, spreading L2
// line requests over the whole 1MB WnnT instead of one hot 16KB chunk.
// ---------------------------------------------------------------------------
__launch_bounds__(512, 1)
__global__ void fused_msg_m(const float* __restrict__ ebf,
                            const float* __restrict__ hid,
                            const _Float16* __restrict__ WnnT,
                            const float* __restrict__ bnn,
                            const int* __restrict__ eidx,
                            _Float16* __restrict__ msgbuf) {
  __shared__ __align__(16) _Float16 Ae[128 * 128];  // 32,768 B, XOR-swizzled
  __shared__ __align__(16) float Hs[64 * 132];      // 33,792 B  Hs[d*132+e]
  const int t = threadIdx.x;       // 0..511
  const int w = t >> 6, l = t & 63, l15 = l & 15, q = l >> 4;
  const int fw = w & 3;            // f cols: fw*16 + l15
  const int eh = w >> 2;           // e half: eh*64
  const int ebase = blockIdx.x * 128;
  const int rot = blockIdx.x & 15;

  // stage Hs (transposed): 128 e x 16 d-quads
#pragma unroll
  for (int i = 0; i < 4; ++i) {
    int g = i * 512 + t;
    int e = g >> 4, d4 = g & 15;
    int r = eidx[ebase + e];
    float4 v = *(const float4*)&hid[(size_t)r * 64 + d4 * 4];
    Hs[(d4 * 4 + 0) * 132 + e] = v.x;
    Hs[(d4 * 4 + 1) * 132 + e] = v.y;
    Hs[(d4 * 4 + 2) * 132 + e] = v.z;
    Hs[(d4 * 4 + 3) * 132 + e] = v.w;
  }
  // stage Ae: 128 edges x 128 k, f32 -> fp16 once, XOR-swizzled 16B blocks
#pragma unroll
  for (int i = 0; i < 4; ++i) {
    int g = i * 512 + t;           // 2048 = 128 e x 16 groups of 8 halves
    int e = g >> 4, kg = g & 15;
    f16x8 v = packh8(&ebf[(size_t)(ebase + e) * 128 + kg * 8]);
    int kgp = kg ^ (e & 15);
    *(f16x8*)&Ae[e * 128 + kgp * 8] = v;
  }

  float msg[4][4];
#pragma unroll
  for (int m = 0; m < 4; ++m)
#pragma unroll
    for (int rr = 0; rr < 4; ++rr) msg[m][rr] = 0.f;

  __syncthreads();

  // B fragment base: lane row within chunk = fw*16+l15, k-offset q*8
  const _Float16* wb = WnnT + (size_t)(fw * 16 + l15) * 128 + q * 8;

#pragma unroll 1
  for (int dgi = 0; dgi < 16; ++dgi) {
    const int dgr = (dgi + rot) & 15;   // de-correlated B sweep
    // stream B for 4 chunks (64 VGPRs, consumed in this body)
    f16x8 bb[4][4];
#pragma unroll
    for (int c = 0; c < 4; ++c) {
      const _Float16* p = wb + (size_t)(dgr * 4 + c) * 8192;
#pragma unroll
      for (int kk = 0; kk < 4; ++kk) bb[c][kk] = *(const f16x8*)(p + kk * 32);
    }
    float bnv[4];
#pragma unroll
    for (int c = 0; c < 4; ++c) bnv[c] = bnn[(dgr * 4 + c) * 64 + fw * 16 + l15];

#pragma unroll
    for (int m = 0; m < 4; ++m) {
      const int arow = (eh * 64 + m * 16 + l15) * 128;
      f32x4 C[4];
#pragma unroll
      for (int c = 0; c < 4; ++c) C[c] = (f32x4){0.f, 0.f, 0.f, 0.f};
#pragma unroll
      for (int kk = 0; kk < 4; ++kk) {
        int kgp = (kk * 4 + q) ^ l15;   // e&15 == l15 for this wave's A rows
        f16x8 a = *(const f16x8*)&Ae[arow + kgp * 8];
#pragma unroll
        for (int c = 0; c < 4; ++c)
          C[c] = __builtin_amdgcn_mfma_f32_16x16x32_f16(a, bb[c][kk], C[c], 0, 0, 0);
      }
#pragma unroll
      for (int c = 0; c < 4; ++c) {
        int d = dgr * 4 + c;
        float4 hv = *(const float4*)&Hs[d * 132 + eh * 64 + m * 16 + q * 4];
        msg[m][0] = fmaf(hv.x, fmaxf(C[c][0] + bnv[c], 0.f), msg[m][0]);
        msg[m][1] = fmaf(hv.y, fmaxf(C[c][1] + bnv[c], 0.f), msg[m][1]);
        msg[m][2] = fmaf(hv.z, fmaxf(C[c][2] + bnv[c], 0.f), msg[m][2]);
        msg[m][3] = fmaf(hv.w, fmaxf(C[c][3] + bnv[c], 0.f), msg[m][3]);
      }
    }
    asm volatile("" ::: "memory");   // keep LDS reads in-loop (no 64-VGPR hoist)
  }

  // plain fp16 stores (no atomics) -> msgbuf[e][f]
#pragma unroll
  for (int m = 0; m < 4; ++m)
#pragma unroll
    for (int rr = 0; rr < 4; ++rr) {
      int e = ebase + eh * 64 + m * 16 + q * 4 + rr;
      msgbuf[(size_t)e * 64 + fw * 16 + l15] = (_Float16)msg[m][rr];
    }
}

// ---------------------------------------------------------------------------
// node_update_g: agg via CSR gather of msgbuf; m = relu(agg + h@W_root+b);
// GRU gates computed gate-column-per-thread (weights read ONCE per block, not
// once per node: old kernel re-read wih/whh ~28MB/dispatch); h in d_out
// updated in place. Block = 16 nodes, 256 threads. LDS ~50KB.
// ---------------------------------------------------------------------------
__launch_bounds__(256)
__global__ void node_update_g(const _Float16* __restrict__ msgbuf,
                              const int* __restrict__ rowptr,
                              const int* __restrict__ eids,
                              float* __restrict__ hid,
                              const float* __restrict__ Wroot,
                              const float* __restrict__ bconv,
                              const float* __restrict__ wih,
                              const float* __restrict__ whh,
                              const float* __restrict__ bih,
                              const float* __restrict__ bhh) {
  __shared__ __align__(16) float shT[64 * 20];   // h^T  [k][nl], stride 20
  __shared__ __align__(16) float smT[64 * 20];   // m^T  [k][nl]
  __shared__ __align__(16) float sg[16 * 384];   // gates
  __shared__ __align__(16) float sW[64 * 64];    // Wroot
  const int t = threadIdx.x;
  const int nb = blockIdx.x * 16;

  // stage Wroot (f32, 16KB)
#pragma unroll
  for (int i = 0; i < 4; ++i) {
    int g = i * 256 + t;
    *(float4*)&sW[g * 4] = *(const float4*)&Wroot[g * 4];
  }
  // stage h transposed
#pragma unroll
  for (int i = 0; i < 4; ++i) {
    int idx = i * 256 + t;
    int nl = idx >> 6, dc = idx & 63;
    shT[dc * 20 + nl] = hid[(size_t)(nb + nl) * 64 + dc];
  }
  __syncthreads();

  // phase 1: gather msg + root matmul -> m (write transposed)
#pragma unroll
  for (int i = 0; i < 4; ++i) {
    int idx = i * 256 + t;
    int nl = idx >> 6, dc = idx & 63;
    int n = nb + nl;
    float acc = bconv[dc];
    int r0 = rowptr[n], r1 = rowptr[n + 1];
    for (int j = r0; j < r1; ++j)
      acc += (float)msgbuf[(size_t)eids[j] * 64 + dc];
    for (int k = 0; k < 64; ++k)
      acc = fmaf(shT[k * 20 + nl], sW[k * 64 + dc], acc);
    smT[dc * 20 + nl] = fmaxf(acc, 0.f);
  }
  __syncthreads();

  // phase 2: gates — thread owns one gate column, accumulates 16 nodes in regs
  for (int p = 0; p < 2; ++p) {
    int j2 = p * 256 + t;
    if (j2 < 384) {
      bool is_ih = (j2 < 192);
      int col = is_ih ? j2 : j2 - 192;
      const float* W = is_ih ? wih : whh;
      float bias = is_ih ? bih[col] : bhh[col];
      const float* inT = is_ih ? smT : shT;
      float a[16];
#pragma unroll
      for (int nl = 0; nl < 16; ++nl) a[nl] = bias;
      for (int k = 0; k < 64; ++k) {
        float wv = W[k * 192 + col];
        float4 v0 = *(const float4*)&inT[k * 20 + 0];
        float4 v1 = *(const float4*)&inT[k * 20 + 4];
        float4 v2 = *(const float4*)&inT[k * 20 + 8];
        float4 v3 = *(const float4*)&inT[k * 20 + 12];
        a[0]  = fmaf(v0.x, wv, a[0]);  a[1]  = fmaf(v0.y, wv, a[1]);
        a[2]  = fmaf(v0.z, wv, a[2]);  a[3]  = fmaf(v0.w, wv, a[3]);
        a[4]  = fmaf(v1.x, wv, a[4]);  a[5]  = fmaf(v1.y, wv, a[5]);
        a[6]  = fmaf(v1.z, wv, a[6]);  a[7]  = fmaf(v1.w, wv, a[7]);
        a[8]  = fmaf(v2.x, wv, a[8]);  a[9]  = fmaf(v2.y, wv, a[9]);
        a[10] = fmaf(v2.z, wv, a[10]); a[11] = fmaf(v2.w, wv, a[11]);
        a[12] = fmaf(v3.x, wv, a[12]); a[13] = fmaf(v3.y, wv, a[13]);
        a[14] = fmaf(v3.z, wv, a[14]); a[15] = fmaf(v3.w, wv, a[15]);
      }
#pragma unroll
      for (int nl = 0; nl < 16; ++nl) sg[nl * 384 + j2] = a[nl];
    }
  }
  __syncthreads();

  // phase 3: GRU elementwise
#pragma unroll
  for (int i = 0; i < 4; ++i) {
    int idx = i * 256 + t;
    int nl = idx >> 6, dc = idx & 63;
    const float* g = &sg[nl * 384];
    float ir = g[dc], iz = g[64 + dc], in_ = g[128 + dc];
    float hr = g[192 + dc], hz = g[256 + dc], hn = g[320 + dc];
    float r = sigm(ir + hr), z = sigm(iz + hz);
    float nc = tanhf(in_ + r * hn);
    hid[(size_t)nb * 64 + idx] = (1.f - z) * nc + z * shT[dc * 20 + nl];
  }
}

// ---------------------------------------------------------------------------
// edge_mlp (MFMA, fp16): e' = relu(relu([h[row]|h[col]|e] @ We1 + b1) @ We2 + b2)
// 64 edges/block. cat staged to LDS as fp16; B fragments direct from global
// (per-wave disjoint rows). Hidden tile Ts in LDS (fp16). f32 in/out, in place.
// ---------------------------------------------------------------------------
__launch_bounds__(256)
__global__ void edge_mlp_m(const float* __restrict__ hid,
                           float* __restrict__ ebf,
                           const int* __restrict__ eidx,
                           const _Float16* __restrict__ We1T,
                           const float* __restrict__ be1,
                           const _Float16* __restrict__ We2T,
                           const float* __restrict__ be2) {
  __shared__ _Float16 As[64 * 264];   // 33,792 B
  __shared__ _Float16 Ts[64 * 136];   // 17,408 B
  const int t = threadIdx.x;
  const int w = t >> 6, l = t & 63, l15 = l & 15, q = l >> 4;
  const int mbase = blockIdx.x * 64;

  for (int g = t; g < 2048; g += 256) {
    int r = g >> 5, kg = g & 31;
    int e = mbase + r;
    const float* src;
    if (kg < 8)       src = &hid[(size_t)eidx[e] * 64 + kg * 8];
    else if (kg < 16) src = &hid[(size_t)eidx[N_EDGES + e] * 64 + (kg - 8) * 8];
    else              src = &ebf[(size_t)e * 128 + (kg - 16) * 8];
    *(f16x8*)&As[r * 264 + kg * 8] = packh8(src);
  }
  __syncthreads();

  f32x4 zero4 = {0.f, 0.f, 0.f, 0.f};
  f32x4 acc[4][2];
#pragma unroll
  for (int m = 0; m < 4; ++m)
#pragma unroll
    for (int nn = 0; nn < 2; ++nn) acc[m][nn] = zero4;

#pragma unroll
  for (int kc = 0; kc < 4; ++kc)
#pragma unroll
    for (int kk = 0; kk < 2; ++kk) {
      int ko = kc * 64 + kk * 32 + q * 8;
      f16x8 b0 = *(const f16x8*)(We1T + (size_t)(w * 32 + l15) * 256 + ko);
      f16x8 b1 = *(const f16x8*)(We1T + (size_t)(w * 32 + 16 + l15) * 256 + ko);
#pragma unroll
      for (int m = 0; m < 4; ++m) {
        f16x8 a = *(const f16x8*)&As[(m * 16 + l15) * 264 + ko];
        acc[m][0] = __builtin_amdgcn_mfma_f32_16x16x32_f16(a, b0, acc[m][0], 0, 0, 0);
        acc[m][1] = __builtin_amdgcn_mfma_f32_16x16x32_f16(a, b1, acc[m][1], 0, 0, 0);
      }
    }

#pragma unroll
  for (int m = 0; m < 4; ++m)
#pragma unroll
    for (int nn = 0; nn < 2; ++nn) {
      int col = w * 32 + nn * 16 + l15;
      float bv = be1[col];
#pragma unroll
      for (int rr = 0; rr < 4; ++rr) {
        int row = m * 16 + q * 4 + rr;
        Ts[row * 136 + col] = (_Float16)fmaxf(acc[m][nn][rr] + bv, 0.f);
      }
    }
  __syncthreads();

  f32x4 acc2[4][2];
#pragma unroll
  for (int m = 0; m < 4; ++m)
#pragma unroll
    for (int nn = 0; nn < 2; ++nn) acc2[m][nn] = zero4;

#pragma unroll
  for (int kc = 0; kc < 2; ++kc)
#pragma unroll
    for (int kk = 0; kk < 2; ++kk) {
      int ko = kc * 64 + kk * 32 + q * 8;
      f16x8 b0 = *(const f16x8*)(We2T + (size_t)(w * 32 + l15) * 128 + ko);
      f16x8 b1 = *(const f16x8*)(We2T + (size_t)(w * 32 + 16 + l15) * 128 + ko);
#pragma unroll
      for (int m = 0; m < 4; ++m) {
        f16x8 a = *(const f16x8*)&Ts[(m * 16 + l15) * 136 + ko];
        acc2[m][0] = __builtin_amdgcn_mfma_f32_16x16x32_f16(a, b0, acc2[m][0], 0, 0, 0);
        acc2[m][1] = __builtin_amdgcn_mfma_f32_16x16x32_f16(a, b1, acc2[m][1], 0, 0, 0);
      }
    }

#pragma unroll
  for (int m = 0; m < 4; ++m)
#pragma unroll
    for (int nn = 0; nn < 2; ++nn) {
      int col = w * 32 + nn * 16 + l15;
      float bv = be2[col];
#pragma unroll
      for (int rr = 0; rr < 4; ++rr) {
        int row = mbase + m * 16 + q * 4 + rr;
        ebf[(size_t)row * 128 + col] = fmaxf(acc2[m][nn][rr] + bv, 0.f);
      }
    }
}

// ---------------------------------------------------------------------------
extern "C" void kernel_launch(void* const* d_in, const int* in_sizes, int n_in,
                              void* d_out, int out_size, void* d_ws, size_t ws_size,
                              hipStream_t stream) {
  const float* nf    = (const float*)d_in[0];
  const float* ea    = (const float*)d_in[1];
  const int*   eidx  = (const int*)d_in[2];
  const float* Wp    = (const float*)d_in[3];
  const float* bp    = (const float*)d_in[4];
  const float* Wpe   = (const float*)d_in[5];
  const float* bpe   = (const float*)d_in[6];
  const float* Wnn   = (const float*)d_in[7];
  const float* bnn   = (const float*)d_in[8];
  const float* Wroot = (const float*)d_in[9];
  const float* bconv = (const float*)d_in[10];
  const float* wih   = (const float*)d_in[11];
  const float* whh   = (const float*)d_in[12];
  const float* bih   = (const float*)d_in[13];
  const float* bhh   = (const float*)d_in[14];
  const float* We1   = (const float*)d_in[15];
  const float* be1   = (const float*)d_in[16];
  const float* We2   = (const float*)d_in[17];
  const float* be2   = (const float*)d_in[18];

  // h and e live in d_out (f32 masters), fully rewritten every launch.
  float* hid = (float*)d_out;                 // 4096*64
  float* ebf = (float*)d_out + 4096 * 64;     // 32768*128

  // workspace: 5,505,152 B
  char* ws = (char*)d_ws;
  _Float16* WnnT   = (_Float16*)(ws + 0);          // 1,048,576
  _Float16* We1T   = (_Float16*)(ws + 1048576);    //    65,536
  _Float16* We2T   = (_Float16*)(ws + 1114112);    //    32,768
  _Float16* msgbuf = (_Float16*)(ws + 1146880);    // 4,194,304
  int*      rowptr = (int*)(ws + 5341184);         //    16,512 (4097 used)
  int*      cursor = (int*)(ws + 5357696);         //    16,384
  int*      eids   = (int*)(ws + 5374080);         //   131,072

  prep_all<<<320, 256, 0, stream>>>(Wnn, We1, We2, WnnT, We1T, We2T);
  proj_node_f<<<1024, 256, 0, stream>>>(nf, Wp, bp, hid);
  proj_edge_f2<<<1024, 256, 0, stream>>>(ea, Wpe, bpe, ebf);

  // CSR of incoming edges per node (built once; edge_index is constant)
  csr_zero<<<16, 256, 0, stream>>>(cursor);          // use cursor as rowcnt
  csr_count<<<128, 256, 0, stream>>>(eidx, cursor);
  csr_scan<<<1, 1024, 0, stream>>>(cursor, rowptr, cursor);
  csr_fill<<<128, 256, 0, stream>>>(eidx, cursor, eids);

  for (int s = 0; s < 3; ++s) {
    fused_msg_m<<<256, 512, 0, stream>>>(ebf, hid, WnnT, bnn, eidx, msgbuf);
    node_update_g<<<256, 256, 0, stream>>>(msgbuf, rowptr, eids, hid, Wroot, bconv,
                                           wih, whh, bih, bhh);
    edge_mlp_m<<<512, 256, 0, stream>>>(hid, ebf, eidx, We1T, be1, We2T, be2);
  }
}

// Round 13
// 469.102 us; speedup vs baseline: 1.1194x; 1.0019x over previous
//
#include <hip/hip_runtime.h>
#include <stdint.h>

typedef __attribute__((ext_vector_type(8))) _Float16 f16x8;
typedef __attribute__((ext_vector_type(4))) float f32x4;

#define N_NODES 4096
#define N_EDGES 32768

__device__ __forceinline__ float sigm(float x) { return 1.f / (1.f + __expf(-x)); }

// pack 8 consecutive f32 -> f16x8 (RNE)
__device__ __forceinline__ f16x8 packh8(const float* p) {
  f16x8 r;
#pragma unroll
  for (int i = 0; i < 8; ++i) r[i] = (_Float16)p[i];
  return r;
}

// ---------------------------------------------------------------------------
// prep (merged): blocks 0..127  -> WnnT[n][k] fp16 from Wnn[k][n] f32
//                blocks 128..319 -> We1T / We2T fp16 transposes
// ---------------------------------------------------------------------------
__global__ void prep_all(const float* __restrict__ Wnn,
                         const float* __restrict__ We1,
                         const float* __restrict__ We2,
                         _Float16* __restrict__ WnnT,
                         _Float16* __restrict__ We1T,
                         _Float16* __restrict__ We2T) {
  __shared__ float tile[128][33];
  const int b = blockIdx.x, t = threadIdx.x;
  if (b < 128) {
    const int nb = b * 32;
    for (int i = 0; i < 16; ++i) {
      int g = i * 256 + t;          // 4096 = 128k x 32n
      int k = g >> 5, j = g & 31;
      tile[k][j] = Wnn[(size_t)k * 4096 + nb + j];
    }
    __syncthreads();
    for (int i = 0; i < 16; ++i) {
      int g = i * 256 + t;
      int j = g >> 7, k = g & 127;
      WnnT[(size_t)(nb + j) * 128 + k] = (_Float16)tile[k][j];
    }
  } else {
    int idx = (b - 128) * 256 + t;   // < 49152
    if (idx < 32768) {
      int n = idx >> 8, k = idx & 255;
      We1T[idx] = (_Float16)We1[(size_t)k * 128 + n];
    } else {
      int j = idx - 32768;
      int n = j >> 7, k = j & 127;
      We2T[j] = (_Float16)We2[(size_t)k * 128 + n];
    }
  }
}

// ---------------------------------------------------------------------------
// CSR build (once per launch; edge_index is launch-constant)
// ---------------------------------------------------------------------------
__global__ void csr_zero(int* __restrict__ rowcnt) {
  rowcnt[blockIdx.x * 256 + threadIdx.x] = 0;
}
__global__ void csr_count(const int* __restrict__ eidx, int* __restrict__ rowcnt) {
  int e = blockIdx.x * 256 + threadIdx.x;
  atomicAdd(&rowcnt[eidx[N_EDGES + e]], 1);
}
__global__ void csr_scan(const int* __restrict__ rowcnt,
                         int* __restrict__ rowptr, int* __restrict__ cursor) {
  __shared__ int part[1024];
  const int t = threadIdx.x;
  const int base = t * 4;
  int s0 = rowcnt[base], s1 = rowcnt[base + 1], s2 = rowcnt[base + 2], s3 = rowcnt[base + 3];
  int sum = s0 + s1 + s2 + s3;
  part[t] = sum;
  __syncthreads();
  for (int off = 1; off < 1024; off <<= 1) {
    int v = (t >= off) ? part[t - off] : 0;
    __syncthreads();
    part[t] += v;
    __syncthreads();
  }
  int excl = part[t] - sum;
  int p0 = excl, p1 = excl + s0, p2 = excl + s0 + s1, p3 = excl + s0 + s1 + s2;
  rowptr[base] = p0; rowptr[base + 1] = p1; rowptr[base + 2] = p2; rowptr[base + 3] = p3;
  cursor[base] = p0; cursor[base + 1] = p1; cursor[base + 2] = p2; cursor[base + 3] = p3;
  if (t == 0) rowptr[4096] = N_EDGES;
}
__global__ void csr_fill(const int* __restrict__ eidx, int* __restrict__ cursor,
                         int* __restrict__ eids) {
  int e = blockIdx.x * 256 + threadIdx.x;
  int slot = atomicAdd(&cursor[eidx[N_EDGES + e]], 1);
  eids[slot] = e;
}

// ---------------------------------------------------------------------------
// proj_node: h = relu(node_feats @ W_p + b_p) -> hid f32 (in d_out)
// ---------------------------------------------------------------------------
__global__ void proj_node_f(const float* __restrict__ nf,
                            const float* __restrict__ Wp,
                            const float* __restrict__ bp,
                            float* __restrict__ h) {
  int idx = blockIdx.x * 256 + threadIdx.x;
  int n = idx >> 6, c = idx & 63;
  float acc = bp[c];
  for (int k = 0; k < 64; ++k)
    acc = fmaf(nf[n * 64 + k], Wp[k * 64 + c], acc);
  h[idx] = fmaxf(acc, 0.f);
}

// ---------------------------------------------------------------------------
// proj_edge: e = relu(edge_attr @ W_pe + b_pe); Wpe cached in LDS; 32 e/block.
// ---------------------------------------------------------------------------
__launch_bounds__(256)
__global__ void proj_edge_f2(const float* __restrict__ ea,
                             const float* __restrict__ Wpe,
                             const float* __restrict__ bpe,
                             float* __restrict__ e) {
  __shared__ float sw[16 * 128];
  __shared__ float sb[128];
  __shared__ float sa[32][17];
  const int t = threadIdx.x;
  const int ebase = blockIdx.x * 32;
  for (int g = t; g < 2048; g += 256) sw[g] = Wpe[g];
  if (t < 128) sb[t] = bpe[t];
  for (int g = t; g < 512; g += 256) {
    int r = g >> 4, k = g & 15;
    sa[r][k] = ea[(size_t)(ebase + r) * 16 + k];
  }
  __syncthreads();
  int c = t & 127, eg = t >> 7;
  float wc[16];
#pragma unroll
  for (int k = 0; k < 16; ++k) wc[k] = sw[k * 128 + c];
  float bv = sb[c];
#pragma unroll
  for (int i = 0; i < 16; ++i) {
    int ee = eg * 16 + i;
    float acc = bv;
#pragma unroll
    for (int k = 0; k < 16; ++k) acc = fmaf(sa[ee][k], wc[k], acc);
    e[(size_t)(ebase + ee) * 128 + c] = fmaxf(acc, 0.f);
  }
}

// ---------------------------------------------------------------------------
// fused_msg (MFMA fp16 v8): 256 blocks x 512 threads.
// R12 post-mortem: no pipe >20% busy; per-dg serial chain (B vmcnt -> MFMA ->
// epilogue VALU -> LDS) with all 8 waves in lockstep => phases serialize.
// v8: (1) PER-WAVE dg rotation (2b+w)&15 -> waves occupy different phases and
// decorrelate L1/L2 bursts; (2) loop-end memory clobber removed, A-LDS address
// made opaque instead (blocks the R6-R8 64-VGPR hoist but lets the compiler
// software-pipeline B loads across dg iterations); (3) bnn bias folded into
// MFMA C-init -> epilogue 2 VALU/element instead of 3.
// ---------------------------------------------------------------------------
__launch_bounds__(512, 1)
__global__ void fused_msg_m(const float* __restrict__ ebf,
                            const float* __restrict__ hid,
                            const _Float16* __restrict__ WnnT,
                            const float* __restrict__ bnn,
                            const int* __restrict__ eidx,
                            _Float16* __restrict__ msgbuf) {
  __shared__ __align__(16) _Float16 Ae[128 * 128];  // 32,768 B, XOR-swizzled
  __shared__ __align__(16) float Hs[64 * 132];      // 33,792 B  Hs[d*132+e]
  const int t = threadIdx.x;       // 0..511
  const int w = t >> 6, l = t & 63, l15 = l & 15, q = l >> 4;
  const int fw = w & 3;            // f cols: fw*16 + l15
  const int eh = w >> 2;           // e half: eh*64
  const int ebase = blockIdx.x * 128;
  const int rot = (blockIdx.x * 2 + w) & 15;   // per-WAVE rotation

  // stage Hs (transposed): 128 e x 16 d-quads
#pragma unroll
  for (int i = 0; i < 4; ++i) {
    int g = i * 512 + t;
    int e = g >> 4, d4 = g & 15;
    int r = eidx[ebase + e];
    float4 v = *(const float4*)&hid[(size_t)r * 64 + d4 * 4];
    Hs[(d4 * 4 + 0) * 132 + e] = v.x;
    Hs[(d4 * 4 + 1) * 132 + e] = v.y;
    Hs[(d4 * 4 + 2) * 132 + e] = v.z;
    Hs[(d4 * 4 + 3) * 132 + e] = v.w;
  }
  // stage Ae: 128 edges x 128 k, f32 -> fp16 once, XOR-swizzled 16B blocks
#pragma unroll
  for (int i = 0; i < 4; ++i) {
    int g = i * 512 + t;           // 2048 = 128 e x 16 groups of 8 halves
    int e = g >> 4, kg = g & 15;
    f16x8 v = packh8(&ebf[(size_t)(ebase + e) * 128 + kg * 8]);
    int kgp = kg ^ (e & 15);
    *(f16x8*)&Ae[e * 128 + kgp * 8] = v;
  }

  float msg[4][4];
#pragma unroll
  for (int m = 0; m < 4; ++m)
#pragma unroll
    for (int rr = 0; rr < 4; ++rr) msg[m][rr] = 0.f;

  __syncthreads();

  // opaque zero: A-LDS addresses depend on it -> reads can't be hoisted out
  // of the dg loop (avoids the 64-VGPR A-hoist), but B loads CAN pipeline.
  int aoff = 0;
  asm volatile("" : "+v"(aoff));

  // B fragment base: lane row within chunk = fw*16+l15, k-offset q*8
  const _Float16* wb = WnnT + (size_t)(fw * 16 + l15) * 128 + q * 8;

#pragma unroll 1
  for (int dgi = 0; dgi < 16; ++dgi) {
    const int dgr = (dgi + rot) & 15;   // per-wave de-correlated B sweep
    f16x8 bb[4][4];
#pragma unroll
    for (int c = 0; c < 4; ++c) {
      const _Float16* p = wb + (size_t)(dgr * 4 + c) * 8192;
#pragma unroll
      for (int kk = 0; kk < 4; ++kk) bb[c][kk] = *(const f16x8*)(p + kk * 32);
    }
    float bnv[4];
#pragma unroll
    for (int c = 0; c < 4; ++c) bnv[c] = bnn[(dgr * 4 + c) * 64 + fw * 16 + l15];

#pragma unroll
    for (int m = 0; m < 4; ++m) {
      const int arow = (eh * 64 + m * 16 + l15) * 128 + aoff;
      f32x4 C[4];
#pragma unroll
      for (int c = 0; c < 4; ++c)
        C[c] = (f32x4){bnv[c], bnv[c], bnv[c], bnv[c]};   // bias pre-loaded
#pragma unroll
      for (int kk = 0; kk < 4; ++kk) {
        int kgp = (kk * 4 + q) ^ l15;   // e&15 == l15 for this wave's A rows
        f16x8 a = *(const f16x8*)&Ae[arow + kgp * 8];
#pragma unroll
        for (int c = 0; c < 4; ++c)
          C[c] = __builtin_amdgcn_mfma_f32_16x16x32_f16(a, bb[c][kk], C[c], 0, 0, 0);
      }
#pragma unroll
      for (int c = 0; c < 4; ++c) {
        int d = dgr * 4 + c;
        float4 hv = *(const float4*)&Hs[d * 132 + eh * 64 + m * 16 + q * 4];
        msg[m][0] = fmaf(hv.x, fmaxf(C[c][0], 0.f), msg[m][0]);
        msg[m][1] = fmaf(hv.y, fmaxf(C[c][1], 0.f), msg[m][1]);
        msg[m][2] = fmaf(hv.z, fmaxf(C[c][2], 0.f), msg[m][2]);
        msg[m][3] = fmaf(hv.w, fmaxf(C[c][3], 0.f), msg[m][3]);
      }
    }
  }

  // plain fp16 stores (no atomics) -> msgbuf[e][f]
#pragma unroll
  for (int m = 0; m < 4; ++m)
#pragma unroll
    for (int rr = 0; rr < 4; ++rr) {
      int e = ebase + eh * 64 + m * 16 + q * 4 + rr;
      msgbuf[(size_t)e * 64 + fw * 16 + l15] = (_Float16)msg[m][rr];
    }
}

// ---------------------------------------------------------------------------
// node_update_g: agg via CSR gather of msgbuf; m = relu(agg + h@W_root+b);
// GRU gates gate-column-per-thread (weights read once per block); h (f32,
// d_out) updated in place. Block = 16 nodes, 256 threads.
// ---------------------------------------------------------------------------
__launch_bounds__(256)
__global__ void node_update_g(const _Float16* __restrict__ msgbuf,
                              const int* __restrict__ rowptr,
                              const int* __restrict__ eids,
                              float* __restrict__ hid,
                              const float* __restrict__ Wroot,
                              const float* __restrict__ bconv,
                              const float* __restrict__ wih,
                              const float* __restrict__ whh,
                              const float* __restrict__ bih,
                              const float* __restrict__ bhh) {
  __shared__ __align__(16) float shT[64 * 20];   // h^T  [k][nl], stride 20
  __shared__ __align__(16) float smT[64 * 20];   // m^T  [k][nl]
  __shared__ __align__(16) float sg[16 * 384];   // gates
  __shared__ __align__(16) float sW[64 * 64];    // Wroot
  const int t = threadIdx.x;
  const int nb = blockIdx.x * 16;

  // stage Wroot (f32, 16KB)
#pragma unroll
  for (int i = 0; i < 4; ++i) {
    int g = i * 256 + t;
    *(float4*)&sW[g * 4] = *(const float4*)&Wroot[g * 4];
  }
  // stage h transposed
#pragma unroll
  for (int i = 0; i < 4; ++i) {
    int idx = i * 256 + t;
    int nl = idx >> 6, dc = idx & 63;
    shT[dc * 20 + nl] = hid[(size_t)(nb + nl) * 64 + dc];
  }
  __syncthreads();

  // phase 1: gather msg + root matmul -> m (write transposed)
#pragma unroll
  for (int i = 0; i < 4; ++i) {
    int idx = i * 256 + t;
    int nl = idx >> 6, dc = idx & 63;
    int n = nb + nl;
    float acc = bconv[dc];
    int r0 = rowptr[n], r1 = rowptr[n + 1];
    for (int j = r0; j < r1; ++j)
      acc += (float)msgbuf[(size_t)eids[j] * 64 + dc];
    for (int k = 0; k < 64; ++k)
      acc = fmaf(shT[k * 20 + nl], sW[k * 64 + dc], acc);
    smT[dc * 20 + nl] = fmaxf(acc, 0.f);
  }
  __syncthreads();

  // phase 2: gates — thread owns one gate column, accumulates 16 nodes in regs
  for (int p = 0; p < 2; ++p) {
    int j2 = p * 256 + t;
    if (j2 < 384) {
      bool is_ih = (j2 < 192);
      int col = is_ih ? j2 : j2 - 192;
      const float* W = is_ih ? wih : whh;
      float bias = is_ih ? bih[col] : bhh[col];
      const float* inT = is_ih ? smT : shT;
      float a[16];
#pragma unroll
      for (int nl = 0; nl < 16; ++nl) a[nl] = bias;
      for (int k = 0; k < 64; ++k) {
        float wv = W[k * 192 + col];
        float4 v0 = *(const float4*)&inT[k * 20 + 0];
        float4 v1 = *(const float4*)&inT[k * 20 + 4];
        float4 v2 = *(const float4*)&inT[k * 20 + 8];
        float4 v3 = *(const float4*)&inT[k * 20 + 12];
        a[0]  = fmaf(v0.x, wv, a[0]);  a[1]  = fmaf(v0.y, wv, a[1]);
        a[2]  = fmaf(v0.z, wv, a[2]);  a[3]  = fmaf(v0.w, wv, a[3]);
        a[4]  = fmaf(v1.x, wv, a[4]);  a[5]  = fmaf(v1.y, wv, a[5]);
        a[6]  = fmaf(v1.z, wv, a[6]);  a[7]  = fmaf(v1.w, wv, a[7]);
        a[8]  = fmaf(v2.x, wv, a[8]);  a[9]  = fmaf(v2.y, wv, a[9]);
        a[10] = fmaf(v2.z, wv, a[10]); a[11] = fmaf(v2.w, wv, a[11]);
        a[12] = fmaf(v3.x, wv, a[12]); a[13] = fmaf(v3.y, wv, a[13]);
        a[14] = fmaf(v3.z, wv, a[14]); a[15] = fmaf(v3.w, wv, a[15]);
      }
#pragma unroll
      for (int nl = 0; nl < 16; ++nl) sg[nl * 384 + j2] = a[nl];
    }
  }
  __syncthreads();

  // phase 3: GRU elementwise
#pragma unroll
  for (int i = 0; i < 4; ++i) {
    int idx = i * 256 + t;
    int nl = idx >> 6, dc = idx & 63;
    const float* g = &sg[nl * 384];
    float ir = g[dc], iz = g[64 + dc], in_ = g[128 + dc];
    float hr = g[192 + dc], hz = g[256 + dc], hn = g[320 + dc];
    float r = sigm(ir + hr), z = sigm(iz + hz);
    float nc = tanhf(in_ + r * hn);
    hid[(size_t)nb * 64 + idx] = (1.f - z) * nc + z * shT[dc * 20 + nl];
  }
}

// ---------------------------------------------------------------------------
// edge_mlp (MFMA, fp16): e' = relu(relu([h[row]|h[col]|e] @ We1 + b1) @ We2 + b2)
// 64 edges/block. cat staged to LDS as fp16; B fragments direct from global
// (per-wave disjoint rows). Hidden tile Ts in LDS (fp16). f32 in/out, in place.
// ---------------------------------------------------------------------------
__launch_bounds__(256)
__global__ void edge_mlp_m(const float* __restrict__ hid,
                           float* __restrict__ ebf,
                           const int* __restrict__ eidx,
                           const _Float16* __restrict__ We1T,
                           const float* __restrict__ be1,
                           const _Float16* __restrict__ We2T,
                           const float* __restrict__ be2) {
  __shared__ _Float16 As[64 * 264];   // 33,792 B
  __shared__ _Float16 Ts[64 * 136];   // 17,408 B
  const int t = threadIdx.x;
  const int w = t >> 6, l = t & 63, l15 = l & 15, q = l >> 4;
  const int mbase = blockIdx.x * 64;

  for (int g = t; g < 2048; g += 256) {
    int r = g >> 5, kg = g & 31;
    int e = mbase + r;
    const float* src;
    if (kg < 8)       src = &hid[(size_t)eidx[e] * 64 + kg * 8];
    else if (kg < 16) src = &hid[(size_t)eidx[N_EDGES + e] * 64 + (kg - 8) * 8];
    else              src = &ebf[(size_t)e * 128 + (kg - 16) * 8];
    *(f16x8*)&As[r * 264 + kg * 8] = packh8(src);
  }
  __syncthreads();

  f32x4 zero4 = {0.f, 0.f, 0.f, 0.f};
  f32x4 acc[4][2];
#pragma unroll
  for (int m = 0; m < 4; ++m)
#pragma unroll
    for (int nn = 0; nn < 2; ++nn) acc[m][nn] = zero4;

#pragma unroll
  for (int kc = 0; kc < 4; ++kc)
#pragma unroll
    for (int kk = 0; kk < 2; ++kk) {
      int ko = kc * 64 + kk * 32 + q * 8;
      f16x8 b0 = *(const f16x8*)(We1T + (size_t)(w * 32 + l15) * 256 + ko);
      f16x8 b1 = *(const f16x8*)(We1T + (size_t)(w * 32 + 16 + l15) * 256 + ko);
#pragma unroll
      for (int m = 0; m < 4; ++m) {
        f16x8 a = *(const f16x8*)&As[(m * 16 + l15) * 264 + ko];
        acc[m][0] = __builtin_amdgcn_mfma_f32_16x16x32_f16(a, b0, acc[m][0], 0, 0, 0);
        acc[m][1] = __builtin_amdgcn_mfma_f32_16x16x32_f16(a, b1, acc[m][1], 0, 0, 0);
      }
    }

#pragma unroll
  for (int m = 0; m < 4; ++m)
#pragma unroll
    for (int nn = 0; nn < 2; ++nn) {
      int col = w * 32 + nn * 16 + l15;
      float bv = be1[col];
#pragma unroll
      for (int rr = 0; rr < 4; ++rr) {
        int row = m * 16 + q * 4 + rr;
        Ts[row * 136 + col] = (_Float16)fmaxf(acc[m][nn][rr] + bv, 0.f);
      }
    }
  __syncthreads();

  f32x4 acc2[4][2];
#pragma unroll
  for (int m = 0; m < 4; ++m)
#pragma unroll
    for (int nn = 0; nn < 2; ++nn) acc2[m][nn] = zero4;

#pragma unroll
  for (int kc = 0; kc < 2; ++kc)
#pragma unroll
    for (int kk = 0; kk < 2; ++kk) {
      int ko = kc * 64 + kk * 32 + q * 8;
      f16x8 b0 = *(const f16x8*)(We2T + (size_t)(w * 32 + l15) * 128 + ko);
      f16x8 b1 = *(const f16x8*)(We2T + (size_t)(w * 32 + 16 + l15) * 128 + ko);
#pragma unroll
      for (int m = 0; m < 4; ++m) {
        f16x8 a = *(const f16x8*)&Ts[(m * 16 + l15) * 136 + ko];
        acc2[m][0] = __builtin_amdgcn_mfma_f32_16x16x32_f16(a, b0, acc2[m][0], 0, 0, 0);
        acc2[m][1] = __builtin_amdgcn_mfma_f32_16x16x32_f16(a, b1, acc2[m][1], 0, 0, 0);
      }
    }

#pragma unroll
  for (int m = 0; m < 4; ++m)
#pragma unroll
    for (int nn = 0; nn < 2; ++nn) {
      int col = w * 32 + nn * 16 + l15;
      float bv = be2[col];
#pragma unroll
      for (int rr = 0; rr < 4; ++rr) {
        int row = mbase + m * 16 + q * 4 + rr;
        ebf[(size_t)row * 128 + col] = fmaxf(acc2[m][nn][rr] + bv, 0.f);
      }
    }
}

// ---------------------------------------------------------------------------
extern "C" void kernel_launch(void* const* d_in, const int* in_sizes, int n_in,
                              void* d_out, int out_size, void* d_ws, size_t ws_size,
                              hipStream_t stream) {
  const float* nf    = (const float*)d_in[0];
  const float* ea    = (const float*)d_in[1];
  const int*   eidx  = (const int*)d_in[2];
  const float* Wp    = (const float*)d_in[3];
  const float* bp    = (const float*)d_in[4];
  const float* Wpe   = (const float*)d_in[5];
  const float* bpe   = (const float*)d_in[6];
  const float* Wnn   = (const float*)d_in[7];
  const float* bnn   = (const float*)d_in[8];
  const float* Wroot = (const float*)d_in[9];
  const float* bconv = (const float*)d_in[10];
  const float* wih   = (const float*)d_in[11];
  const float* whh   = (const float*)d_in[12];
  const float* bih   = (const float*)d_in[13];
  const float* bhh   = (const float*)d_in[14];
  const float* We1   = (const float*)d_in[15];
  const float* be1   = (const float*)d_in[16];
  const float* We2   = (const float*)d_in[17];
  const float* be2   = (const float*)d_in[18];

  // h and e live in d_out (f32 masters), fully rewritten every launch.
  float* hid = (float*)d_out;                 // 4096*64
  float* ebf = (float*)d_out + 4096 * 64;     // 32768*128

  // workspace: 5,505,152 B
  char* ws = (char*)d_ws;
  _Float16* WnnT   = (_Float16*)(ws + 0);          // 1,048,576
  _Float16* We1T   = (_Float16*)(ws + 1048576);    //    65,536
  _Float16* We2T   = (_Float16*)(ws + 1114112);    //    32,768
  _Float16* msgbuf = (_Float16*)(ws + 1146880);    // 4,194,304
  int*      rowptr = (int*)(ws + 5341184);         //    16,512 (4097 used)
  int*      cursor = (int*)(ws + 5357696);         //    16,384
  int*      eids   = (int*)(ws + 5374080);         //   131,072

  prep_all<<<320, 256, 0, stream>>>(Wnn, We1, We2, WnnT, We1T, We2T);
  proj_node_f<<<1024, 256, 0, stream>>>(nf, Wp, bp, hid);
  proj_edge_f2<<<1024, 256, 0, stream>>>(ea, Wpe, bpe, ebf);

  // CSR of incoming edges per node (built once; edge_index is constant)
  csr_zero<<<16, 256, 0, stream>>>(cursor);          // use cursor as rowcnt
  csr_count<<<128, 256, 0, stream>>>(eidx, cursor);
  csr_scan<<<1, 1024, 0, stream>>>(cursor, rowptr, cursor);
  csr_fill<<<128, 256, 0, stream>>>(eidx, cursor, eids);

  for (int s = 0; s < 3; ++s) {
    fused_msg_m<<<256, 512, 0, stream>>>(ebf, hid, WnnT, bnn, eidx, msgbuf);
    node_update_g<<<256, 256, 0, stream>>>(msgbuf, rowptr, eids, hid, Wroot, bconv,
                                           wih, whh, bih, bhh);
    edge_mlp_m<<<512, 256, 0, stream>>>(hid, ebf, eidx, We1T, be1, We2T, be2);
  }
}